// Round 7
// baseline (194.350 us; speedup 1.0000x reference)
//
#include <hip/hip_runtime.h>
#include <math.h>

#define EPS 1e-5f
#define NBATCH 8
#define NPTS 2048
#define KNB 16
#define BIG 3.2e38f

// ---- workspace layout (in floats) — proven r4 footprint (7.34 MB) ----
#define WS_PRE 0                            // 16384*24
#define WS_AUX (16384 * 24)                 // 16384*72
#define WS_IDX (WS_AUX + 16384 * 72)        // 16384*16 ints

// Kernel 1: fold BN (per-block in LDS) + pre + aux. (r4-proven logic)
__global__ __launch_bounds__(256) void pack_pre_kernel(
    const float* __restrict__ x,
    const float* __restrict__ w_pre, const float* __restrict__ b_pre,
    const float* __restrict__ g_pre, const float* __restrict__ be_pre,
    const float* __restrict__ m_pre, const float* __restrict__ v_pre,
    const float* __restrict__ w1, const float* __restrict__ g1,
    const float* __restrict__ be1, const float* __restrict__ m1,
    const float* __restrict__ v1,
    const float* __restrict__ w2, const float* __restrict__ g2,
    const float* __restrict__ be2, const float* __restrict__ m2,
    const float* __restrict__ v2, const float* __restrict__ w3,
    float* __restrict__ pre, float* __restrict__ aux) {
  __shared__ float fwp[72], fbp[24], fw1[576], fb1[12], fw2[720], fb2[12];
  int tid = threadIdx.x;
  if (tid < 72) { int o = tid / 3; fwp[tid] = w_pre[tid] * (g_pre[o] / sqrtf(v_pre[o] + EPS)); }
  if (tid < 24) { float inv = g_pre[tid] / sqrtf(v_pre[tid] + EPS);
                  fbp[tid] = (b_pre[tid] - m_pre[tid]) * inv + be_pre[tid]; }
  for (int j = tid; j < 576; j += 256) { int o = j / 48; fw1[j] = w1[j] * (g1[o] / sqrtf(v1[o] + EPS)); }
  if (tid < 12) { float inv = g1[tid] / sqrtf(v1[tid] + EPS); fb1[tid] = be1[tid] - m1[tid] * inv; }
  for (int j = tid; j < 720; j += 256) { int o = j / 60; fw2[j] = w2[j] * (g2[o] / sqrtf(v2[o] + EPS)); }
  if (tid < 12) { float inv = g2[tid] / sqrtf(v2[tid] + EPS); fb2[tid] = be2[tid] - m2[tid] * inv; }
  __syncthreads();
  int p = blockIdx.x * 256 + tid;          // 0..16383
  int b = p >> 11, n = p & (NPTS - 1);
  const float* xb = x + (size_t)b * 3 * NPTS;
  float x0 = xb[n], x1 = xb[NPTS + n], x2 = xb[2 * NPTS + n];
  float pr[24];
#pragma unroll
  for (int c = 0; c < 24; ++c) {
    float v = fmaf(fwp[c * 3 + 0], x0,
              fmaf(fwp[c * 3 + 1], x1,
              fmaf(fwp[c * 3 + 2], x2, fbp[c])));
    pr[c] = fmaxf(v, 0.f);
  }
  float4* o4 = (float4*)(pre + (size_t)p * 24);
#pragma unroll
  for (int i = 0; i < 6; ++i)
    o4[i] = make_float4(pr[4*i], pr[4*i+1], pr[4*i+2], pr[4*i+3]);
  float* A = aux + (size_t)p * 72;
#pragma unroll
  for (int o = 0; o < 12; ++o) {
    float u1 = fb1[o], a1 = 0.f, u2 = fb2[o], a2 = 0.f, u3 = 0.f, a3 = 0.f;
#pragma unroll
    for (int i = 0; i < 24; ++i) {
      u1 = fmaf(fw1[o*48 + i],      pr[i], u1);
      a1 = fmaf(fw1[o*48 + 24 + i], pr[i], a1);
      u2 = fmaf(fw2[o*60 + 12 + i], pr[i], u2);
      a2 = fmaf(fw2[o*60 + 36 + i], pr[i], a2);
      u3 = fmaf(w3[o*72 + 24 + i],  pr[i], u3);
      a3 = fmaf(w3[o*72 + 48 + i],  pr[i], a3);
    }
    A[o] = u1; A[12+o] = u2; A[24+o] = u3;
    A[36+o] = a1; A[48+o] = a2; A[60+o] = a3;
  }
}

// Exact 16-NN — VERBATIM r4 fused-kernel knn branch (proven), standalone.
// 512 thr = 32 points x 16 slices of 128 candidates; LDS-staged coords.
#define KNN_LDS 54400
__global__ __launch_bounds__(512) void knn_kernel(
    const float* __restrict__ x, int* __restrict__ knn_out) {
  extern __shared__ char smem[];
  float4* C4   = (float4*)smem;              // [2048] (2x,2y,2z,sq), 32 KB
  float* slist = (float*)(smem + 32768);     // [8 lists][16 vals][32 pts], 16 KB
  float* sd2   = (float*)(smem + 49152);     // [32][20]
  int*   sidx  = (int*)(smem + 51712);       // [32][20]
  int*   scnt  = (int*)(smem + 54272);       // [32]
  int tid = threadIdx.x;
  int b = blockIdx.x >> 6, chunk = blockIdx.x & 63;
  const float* xb = x + (size_t)b * 3 * NPTS;
  for (int j = tid; j < NPTS; j += 512) {
    float xx = xb[j], yy = xb[NPTS + j], zz = xb[2 * NPTS + j];
    float sq = __fadd_rn(__fadd_rn(__fmul_rn(xx, xx), __fmul_rn(yy, yy)),
                         __fmul_rn(zz, zz));
    // store 2-scaled coords: x*(2xj) == 2*(x*xj) exactly (exponent shift)
    C4[j] = make_float4(2.0f * xx, 2.0f * yy, 2.0f * zz, sq);
  }
  for (int j = tid; j < 32 * 20; j += 512) sidx[j] = 0;
  if (tid < 32) scnt[tid] = 0;
  __syncthreads();
  int p = tid & 31, s = tid >> 5;            // point 0..31, slice 0..15
  int n = chunk * 32 + p;
  float4 me4 = C4[n];
  float mex = 0.5f * me4.x, mey = 0.5f * me4.y, mez = 0.5f * me4.z;
  float sqn = me4.w;
  const float4* Cs = C4 + s * 128;
  int selfc = n - s * 128;                   // in [0,128) only for self slice
  // Phase 1: branchless sorted-16 (values only)
  float L[16];
#pragma unroll
  for (int t = 0; t < 16; ++t) L[t] = BIG;
#pragma unroll 4
  for (int c = 0; c < 128; ++c) {
    float4 q = Cs[c];
    float dot2 = __fadd_rn(__fadd_rn(__fmul_rn(mex, q.x), __fmul_rn(mey, q.y)),
                           __fmul_rn(mez, q.z));
    float d2 = __fsub_rn(__fadd_rn(sqn, q.w), dot2);
    d2 = (c == selfc) ? BIG : d2;
#pragma unroll
    for (int t = 15; t >= 1; --t) L[t] = fminf(fmaxf(L[t-1], d2), L[t]);
    L[0] = fminf(L[0], d2);
  }
  // wave-level merge of slice pairs (s, s^1) via shfl: 16 lists -> 8
  // (wave = 2 slices x 32 points; lane^32 = same point, other slice)
  {
    float bb[16], m16[16];
#pragma unroll
    for (int i = 0; i < 16; ++i) bb[i] = __shfl_xor(L[i], 32, 64);
#pragma unroll
    for (int i = 0; i < 16; ++i) m16[i] = fminf(L[i], bb[15 - i]);
#pragma unroll
    for (int d = 8; d >= 1; d >>= 1) {
#pragma unroll
      for (int i = 0; i < 16; ++i) {
        if (!(i & d)) {
          float lo = fminf(m16[i], m16[i | d]);
          float hi = fmaxf(m16[i], m16[i | d]);
          m16[i] = lo; m16[i | d] = hi;
        }
      }
    }
    if (!(s & 1)) {
#pragma unroll
      for (int i = 0; i < 16; ++i) slist[((s >> 1) * 16 + i) * 32 + p] = m16[i];
    }
  }
  __syncthreads();
  // Phase 2: merge tree 8 -> 4 -> 2 -> 1 lists (load/barrier/store per level)
  for (int W = 4; W >= 1; W >>= 1) {
    int w = tid >> 5;
    bool act = (w < W);
    float a[16], bb[16];
    if (act) {
#pragma unroll
      for (int i = 0; i < 16; ++i) a[i]  = slist[((2 * w) * 16 + i) * 32 + p];
#pragma unroll
      for (int i = 0; i < 16; ++i) bb[i] = slist[((2 * w + 1) * 16 + i) * 32 + p];
    }
    __syncthreads();
    if (act) {
      float m16[16];
#pragma unroll
      for (int i = 0; i < 16; ++i) m16[i] = fminf(a[i], bb[15 - i]);
#pragma unroll
      for (int d = 8; d >= 1; d >>= 1) {
#pragma unroll
        for (int i = 0; i < 16; ++i) {
          if (!(i & d)) {
            float lo = fminf(m16[i], m16[i | d]);
            float hi = fmaxf(m16[i], m16[i | d]);
            m16[i] = lo; m16[i | d] = hi;
          }
        }
      }
#pragma unroll
      for (int i = 0; i < 16; ++i) slist[(w * 16 + i) * 32 + p] = m16[i];
    }
    __syncthreads();
  }
  float tau = slist[15 * 32 + p];            // exact 16th smallest (self excluded)
  // Phase 3: rescan, collect indices with d2 <= tau
#pragma unroll 4
  for (int c = 0; c < 128; ++c) {
    float4 q = Cs[c];
    float dot2 = __fadd_rn(__fadd_rn(__fmul_rn(mex, q.x), __fmul_rn(mey, q.y)),
                           __fmul_rn(mez, q.z));
    float d2 = __fsub_rn(__fadd_rn(sqn, q.w), dot2);
    int j = s * 128 + c;
    if (d2 <= tau && j != n) {
      int pos = atomicAdd(&scnt[p], 1);
      if (pos < 20) { sd2[p * 20 + pos] = d2; sidx[p * 20 + pos] = j; }
    }
  }
  __syncthreads();
  // Phase 4: rare tie fixup — keep 16 smallest by (d2, idx) lexicographic
  if (tid < 32) {
    int c = scnt[tid]; if (c > 20) c = 20;
    if (c > 16) {
      for (int t = 0; t < 16; ++t) {
        int best = t;
        for (int u = t + 1; u < c; ++u) {
          float da = sd2[tid * 20 + u], db = sd2[tid * 20 + best];
          int ia = sidx[tid * 20 + u], ib = sidx[tid * 20 + best];
          if (da < db || (da == db && ia < ib)) best = u;
        }
        float td = sd2[tid * 20 + t]; sd2[tid * 20 + t] = sd2[tid * 20 + best]; sd2[tid * 20 + best] = td;
        int ti = sidx[tid * 20 + t]; sidx[tid * 20 + t] = sidx[tid * 20 + best]; sidx[tid * 20 + best] = ti;
      }
    }
  }
  __syncthreads();
  {
    int pp = tid >> 4, kk = tid & 15;        // 512 threads = 32 pts x 16 nbrs
    knn_out[((size_t)b * NPTS + chunk * 32 + pp) * KNB + kk] = sidx[pp * 20 + kk];
  }
}

// Fused edge-MLP + max. 16 lanes/point; neighbor-dependent 12x12 blocks only.
__global__ __launch_bounds__(256) void mlp_kernel(
    const float* __restrict__ pre, const float* __restrict__ aux,
    const int* __restrict__ knn, const float* __restrict__ x,
    const float* __restrict__ w2, const float* __restrict__ g2,
    const float* __restrict__ v2, const float* __restrict__ w3,
    float* __restrict__ out) {
  __shared__ float sW2h[144], sW3h2[144], sW3h1[144];
  __shared__ float sout[87 * 16];
  int tid = threadIdx.x;
  if (tid < 144) {
    int o = tid / 12, i = tid - o * 12;
    float inv2 = g2[o] / sqrtf(v2[o] + EPS);
    sW2h[tid]  = w2[o * 60 + i] * inv2;
    sW3h2[tid] = w3[o * 72 + i];
    sW3h1[tid] = w3[o * 72 + 12 + i];
  }
  __syncthreads();
  int k = tid & 15, pl = tid >> 4;
  int p = blockIdx.x * 16 + pl;
  int b = p >> 11, n = p & (NPTS - 1);
  int nb = knn[(size_t)p * KNB + k];
  const float4* u4 = (const float4*)(aux + (size_t)p * 72);
  const float4* a4 = (const float4*)(aux + ((size_t)(b << 11) + nb) * 72 + 36);
  float uc[36], av[36];
#pragma unroll
  for (int i = 0; i < 9; ++i) {
    float4 t = u4[i];
    uc[4*i] = t.x; uc[4*i+1] = t.y; uc[4*i+2] = t.z; uc[4*i+3] = t.w;
    float4 t2 = a4[i];
    av[4*i] = t2.x; av[4*i+1] = t2.y; av[4*i+2] = t2.z; av[4*i+3] = t2.w;
  }
  float h1[12], h2[12], h3[12];
#pragma unroll
  for (int o = 0; o < 12; ++o) h1[o] = fmaxf(uc[o] + av[o], 0.f);
#pragma unroll
  for (int o = 0; o < 12; ++o) {
    float a = uc[12 + o] + av[12 + o];
#pragma unroll
    for (int i = 0; i < 12; ++i) a = fmaf(sW2h[o * 12 + i], h1[i], a);
    h2[o] = fmaxf(a, 0.f);
  }
#pragma unroll
  for (int o = 0; o < 12; ++o) {
    float a = uc[24 + o] + av[24 + o];
#pragma unroll
    for (int i = 0; i < 12; ++i) a = fmaf(sW3h2[o * 12 + i], h2[i], a);
#pragma unroll
    for (int i = 0; i < 12; ++i) a = fmaf(sW3h1[o * 12 + i], h1[i], a);
    h3[o] = a;
  }
  float nbf[24];
  const float4* pn4 = (const float4*)(pre + ((size_t)(b << 11) + nb) * 24);
#pragma unroll
  for (int i = 0; i < 6; ++i) {
    float4 t = pn4[i];
    nbf[4*i] = t.x; nbf[4*i+1] = t.y; nbf[4*i+2] = t.z; nbf[4*i+3] = t.w;
  }
#pragma unroll
  for (int m = 1; m < 16; m <<= 1) {
#pragma unroll
    for (int o = 0; o < 12; ++o) {
      h1[o] = fmaxf(h1[o], __shfl_xor(h1[o], m, 16));
      h2[o] = fmaxf(h2[o], __shfl_xor(h2[o], m, 16));
      h3[o] = fmaxf(h3[o], __shfl_xor(h3[o], m, 16));
    }
#pragma unroll
    for (int i = 0; i < 24; ++i)
      nbf[i] = fmaxf(nbf[i], __shfl_xor(nbf[i], m, 16));
  }
  if (k == 0) {
    const float4* c4 = (const float4*)(pre + (size_t)p * 24);
#pragma unroll
    for (int o = 0; o < 12; ++o) {
      sout[(0  + o) * 16 + pl] = h3[o];
      sout[(12 + o) * 16 + pl] = h2[o];
      sout[(24 + o) * 16 + pl] = h1[o];
    }
#pragma unroll
    for (int i = 0; i < 6; ++i) {
      float4 t = c4[i];
      sout[(36 + 4*i    ) * 16 + pl] = t.x;
      sout[(36 + 4*i + 1) * 16 + pl] = t.y;
      sout[(36 + 4*i + 2) * 16 + pl] = t.z;
      sout[(36 + 4*i + 3) * 16 + pl] = t.w;
    }
#pragma unroll
    for (int i = 0; i < 24; ++i) sout[(60 + i) * 16 + pl] = nbf[i];
    const float* xb = x + (size_t)b * 3 * NPTS + n;
    sout[84 * 16 + pl] = xb[0];
    sout[85 * 16 + pl] = xb[NPTS];
    sout[86 * 16 + pl] = xb[2 * NPTS];
  }
  __syncthreads();
  int n0 = (blockIdx.x * 16) & (NPTS - 1);
  float* ob = out + (size_t)b * 87 * NPTS;
  for (int j2 = tid; j2 < 87 * 16; j2 += 256) {
    int c = j2 >> 4, i = j2 & 15;
    ob[(size_t)c * NPTS + n0 + i] = sout[j2];
  }
}

extern "C" void kernel_launch(void* const* d_in, const int* in_sizes, int n_in,
                              void* d_out, int out_size, void* d_ws, size_t ws_size,
                              hipStream_t stream) {
  (void)in_sizes; (void)n_in; (void)out_size; (void)ws_size;
  const float* x     = (const float*)d_in[0];
  const float* w_pre = (const float*)d_in[1];
  const float* b_pre = (const float*)d_in[2];
  const float* g_pre = (const float*)d_in[3];
  const float* be_pre= (const float*)d_in[4];
  const float* m_pre = (const float*)d_in[5];
  const float* v_pre = (const float*)d_in[6];
  const float* w1    = (const float*)d_in[7];
  const float* g1    = (const float*)d_in[8];
  const float* be1   = (const float*)d_in[9];
  const float* m1    = (const float*)d_in[10];
  const float* v1    = (const float*)d_in[11];
  const float* w2    = (const float*)d_in[12];
  const float* g2    = (const float*)d_in[13];
  const float* be2   = (const float*)d_in[14];
  const float* m2    = (const float*)d_in[15];
  const float* v2    = (const float*)d_in[16];
  const float* w3    = (const float*)d_in[17];
  float* ws  = (float*)d_ws;
  float* pre = ws + WS_PRE;
  float* aux = ws + WS_AUX;
  int*   knn = (int*)(ws + WS_IDX);
  float* out = (float*)d_out;

  pack_pre_kernel<<<64, 256, 0, stream>>>(
      x, w_pre, b_pre, g_pre, be_pre, m_pre, v_pre,
      w1, g1, be1, m1, v1, w2, g2, be2, m2, v2, w3,
      pre, aux);
  knn_kernel<<<NBATCH * 64, 512, KNN_LDS, stream>>>(x, knn);
  mlp_kernel<<<NBATCH * NPTS / 16, 256, 0, stream>>>(pre, aux, knn, x,
                                                     w2, g2, v2, w3, out);
}

// Round 8
// 178.095 us; speedup vs baseline: 1.0913x; 1.0913x over previous
//
#include <hip/hip_runtime.h>
#include <math.h>

#define EPS 1e-5f
#define NBATCH 8
#define NPTS 2048
#define KNB 16
#define BIG 3.2e38f

// ---- workspace layout (in floats) — proven r4 footprint (7.34 MB) ----
#define WS_PRE 0                            // 16384*24
#define WS_AUX (16384 * 24)                 // 16384*72
#define WS_IDX (WS_AUX + 16384 * 72)        // 16384*16 ints

// Fused kernel: exact 16-NN (verbatim r7 phases) + embedded pre/aux for the
// block's own 32 points. 512 blocks x 512 thr; static LDS ~60 KB (2/CU).
__global__ __launch_bounds__(512) void knnpre_kernel(
    const float* __restrict__ x,
    const float* __restrict__ w_pre, const float* __restrict__ b_pre,
    const float* __restrict__ g_pre, const float* __restrict__ be_pre,
    const float* __restrict__ m_pre, const float* __restrict__ v_pre,
    const float* __restrict__ w1, const float* __restrict__ g1,
    const float* __restrict__ be1, const float* __restrict__ m1,
    const float* __restrict__ v1,
    const float* __restrict__ w2, const float* __restrict__ g2,
    const float* __restrict__ be2, const float* __restrict__ m2,
    const float* __restrict__ v2, const float* __restrict__ w3,
    float* __restrict__ pre, float* __restrict__ aux,
    int* __restrict__ knn_out) {
  __shared__ float4 C4[NPTS];                // 32 KB (2x,2y,2z,sq)
  __shared__ float slist[8 * 16 * 32];       // 16 KB
  __shared__ float sd2[32 * 20];
  __shared__ int   sidx[32 * 20];
  __shared__ int   scnt[32];
  __shared__ float fwp[72], fbp[24], fw1[576], fb1[12], fw2[720], fb2[12];
  int tid = threadIdx.x;
  int b = blockIdx.x >> 6, chunk = blockIdx.x & 63;
  const float* xb = x + (size_t)b * 3 * NPTS;
  for (int j = tid; j < NPTS; j += 512) {
    float xx = xb[j], yy = xb[NPTS + j], zz = xb[2 * NPTS + j];
    float sq = __fadd_rn(__fadd_rn(__fmul_rn(xx, xx), __fmul_rn(yy, yy)),
                         __fmul_rn(zz, zz));
    // store 2-scaled coords: x*(2xj) == 2*(x*xj) exactly (exponent shift)
    C4[j] = make_float4(2.0f * xx, 2.0f * yy, 2.0f * zz, sq);
  }
  // fold BN into weights (LDS), same formulas as proven pack_pre
  if (tid < 72) { int o = tid / 3; fwp[tid] = w_pre[tid] * (g_pre[o] / sqrtf(v_pre[o] + EPS)); }
  if (tid < 24) { float inv = g_pre[tid] / sqrtf(v_pre[tid] + EPS);
                  fbp[tid] = (b_pre[tid] - m_pre[tid]) * inv + be_pre[tid]; }
  for (int j = tid; j < 576; j += 512) { int o = j / 48; fw1[j] = w1[j] * (g1[o] / sqrtf(v1[o] + EPS)); }
  if (tid < 12) { float inv = g1[tid] / sqrtf(v1[tid] + EPS); fb1[tid] = be1[tid] - m1[tid] * inv; }
  for (int j = tid; j < 720; j += 512) { int o = j / 60; fw2[j] = w2[j] * (g2[o] / sqrtf(v2[o] + EPS)); }
  if (tid < 12) { float inv = g2[tid] / sqrtf(v2[tid] + EPS); fb2[tid] = be2[tid] - m2[tid] * inv; }
  for (int j = tid; j < 32 * 20; j += 512) sidx[j] = 0;
  if (tid < 32) scnt[tid] = 0;
  __syncthreads();
  // ---- embedded pre + aux for this block's 32 points (16 thr/point) ----
  {
    int pi = tid >> 4, q = tid & 15;         // point 0..31, part 0..15
    int pn = chunk * 32 + pi;
    int gp = (b << 11) + pn;                 // global point index
    float4 cc = C4[pn];
    float x0 = 0.5f * cc.x, x1 = 0.5f * cc.y, x2 = 0.5f * cc.z;  // exact
    float pr[24];
#pragma unroll
    for (int c = 0; c < 24; ++c) {
      float v = fmaf(fwp[c * 3 + 0], x0,
                fmaf(fwp[c * 3 + 1], x1,
                fmaf(fwp[c * 3 + 2], x2, fbp[c])));
      pr[c] = fmaxf(v, 0.f);
    }
    if (q < 12) {
      int o = q;
      float u1 = fb1[o], a1 = 0.f, u2 = fb2[o], a2 = 0.f, u3 = 0.f, a3 = 0.f;
#pragma unroll
      for (int i = 0; i < 24; ++i) {
        u1 = fmaf(fw1[o*48 + i],      pr[i], u1);
        a1 = fmaf(fw1[o*48 + 24 + i], pr[i], a1);
        u2 = fmaf(fw2[o*60 + 12 + i], pr[i], u2);
        a2 = fmaf(fw2[o*60 + 36 + i], pr[i], a2);
        u3 = fmaf(w3[o*72 + 24 + i],  pr[i], u3);
        a3 = fmaf(w3[o*72 + 48 + i],  pr[i], a3);
      }
      float* A = aux + (size_t)gp * 72;
      A[o] = u1; A[12+o] = u2; A[24+o] = u3;
      A[36+o] = a1; A[48+o] = a2; A[60+o] = a3;
    } else {
      int s0 = (q - 12) * 6;                 // 4 threads x 6 values = pre[24]
      float* P = pre + (size_t)gp * 24;
#pragma unroll
      for (int i = 0; i < 6; ++i) P[s0 + i] = pr[s0 + i];
    }
  }
  // ---- exact 16-NN (verbatim r7 phases) ----
  int p = tid & 31, s = tid >> 5;            // point 0..31, slice 0..15
  int n = chunk * 32 + p;
  float4 me4 = C4[n];
  float mex = 0.5f * me4.x, mey = 0.5f * me4.y, mez = 0.5f * me4.z;
  float sqn = me4.w;
  const float4* Cs = C4 + s * 128;
  int selfc = n - s * 128;                   // in [0,128) only for self slice
  // Phase 1: branchless sorted-16 (values only)
  float L[16];
#pragma unroll
  for (int t = 0; t < 16; ++t) L[t] = BIG;
#pragma unroll 4
  for (int c = 0; c < 128; ++c) {
    float4 q = Cs[c];
    float dot2 = __fadd_rn(__fadd_rn(__fmul_rn(mex, q.x), __fmul_rn(mey, q.y)),
                           __fmul_rn(mez, q.z));
    float d2 = __fsub_rn(__fadd_rn(sqn, q.w), dot2);
    d2 = (c == selfc) ? BIG : d2;
#pragma unroll
    for (int t = 15; t >= 1; --t) L[t] = fminf(fmaxf(L[t-1], d2), L[t]);
    L[0] = fminf(L[0], d2);
  }
  // wave-level merge of slice pairs (s, s^1) via shfl: 16 lists -> 8
  {
    float bb[16], m16[16];
#pragma unroll
    for (int i = 0; i < 16; ++i) bb[i] = __shfl_xor(L[i], 32, 64);
#pragma unroll
    for (int i = 0; i < 16; ++i) m16[i] = fminf(L[i], bb[15 - i]);
#pragma unroll
    for (int d = 8; d >= 1; d >>= 1) {
#pragma unroll
      for (int i = 0; i < 16; ++i) {
        if (!(i & d)) {
          float lo = fminf(m16[i], m16[i | d]);
          float hi = fmaxf(m16[i], m16[i | d]);
          m16[i] = lo; m16[i | d] = hi;
        }
      }
    }
    if (!(s & 1)) {
#pragma unroll
      for (int i = 0; i < 16; ++i) slist[((s >> 1) * 16 + i) * 32 + p] = m16[i];
    }
  }
  __syncthreads();
  // Phase 2: merge tree 8 -> 4 -> 2 -> 1 lists (load/barrier/store per level)
  for (int W = 4; W >= 1; W >>= 1) {
    int w = tid >> 5;
    bool act = (w < W);
    float a[16], bb[16];
    if (act) {
#pragma unroll
      for (int i = 0; i < 16; ++i) a[i]  = slist[((2 * w) * 16 + i) * 32 + p];
#pragma unroll
      for (int i = 0; i < 16; ++i) bb[i] = slist[((2 * w + 1) * 16 + i) * 32 + p];
    }
    __syncthreads();
    if (act) {
      float m16[16];
#pragma unroll
      for (int i = 0; i < 16; ++i) m16[i] = fminf(a[i], bb[15 - i]);
#pragma unroll
      for (int d = 8; d >= 1; d >>= 1) {
#pragma unroll
        for (int i = 0; i < 16; ++i) {
          if (!(i & d)) {
            float lo = fminf(m16[i], m16[i | d]);
            float hi = fmaxf(m16[i], m16[i | d]);
            m16[i] = lo; m16[i | d] = hi;
          }
        }
      }
#pragma unroll
      for (int i = 0; i < 16; ++i) slist[(w * 16 + i) * 32 + p] = m16[i];
    }
    __syncthreads();
  }
  float tau = slist[15 * 32 + p];            // exact 16th smallest (self excluded)
  // Phase 3: rescan, collect indices with d2 <= tau
#pragma unroll 4
  for (int c = 0; c < 128; ++c) {
    float4 q = Cs[c];
    float dot2 = __fadd_rn(__fadd_rn(__fmul_rn(mex, q.x), __fmul_rn(mey, q.y)),
                           __fmul_rn(mez, q.z));
    float d2 = __fsub_rn(__fadd_rn(sqn, q.w), dot2);
    int j = s * 128 + c;
    if (d2 <= tau && j != n) {
      int pos = atomicAdd(&scnt[p], 1);
      if (pos < 20) { sd2[p * 20 + pos] = d2; sidx[p * 20 + pos] = j; }
    }
  }
  __syncthreads();
  // Phase 4: rare tie fixup — keep 16 smallest by (d2, idx) lexicographic
  if (tid < 32) {
    int c = scnt[tid]; if (c > 20) c = 20;
    if (c > 16) {
      for (int t = 0; t < 16; ++t) {
        int best = t;
        for (int u = t + 1; u < c; ++u) {
          float da = sd2[tid * 20 + u], db = sd2[tid * 20 + best];
          int ia = sidx[tid * 20 + u], ib = sidx[tid * 20 + best];
          if (da < db || (da == db && ia < ib)) best = u;
        }
        float td = sd2[tid * 20 + t]; sd2[tid * 20 + t] = sd2[tid * 20 + best]; sd2[tid * 20 + best] = td;
        int ti = sidx[tid * 20 + t]; sidx[tid * 20 + t] = sidx[tid * 20 + best]; sidx[tid * 20 + best] = ti;
      }
    }
  }
  __syncthreads();
  {
    int pp = tid >> 4, kk = tid & 15;        // 512 threads = 32 pts x 16 nbrs
    knn_out[((size_t)b * NPTS + chunk * 32 + pp) * KNB + kk] = sidx[pp * 20 + kk];
  }
}

// Fused edge-MLP + max. 16 lanes/point; neighbor-dependent 12x12 blocks only.
__global__ __launch_bounds__(256) void mlp_kernel(
    const float* __restrict__ pre, const float* __restrict__ aux,
    const int* __restrict__ knn, const float* __restrict__ x,
    const float* __restrict__ w2, const float* __restrict__ g2,
    const float* __restrict__ v2, const float* __restrict__ w3,
    float* __restrict__ out) {
  __shared__ float sW2h[144], sW3h2[144], sW3h1[144];
  __shared__ float sout[87 * 16];
  int tid = threadIdx.x;
  if (tid < 144) {
    int o = tid / 12, i = tid - o * 12;
    float inv2 = g2[o] / sqrtf(v2[o] + EPS);
    sW2h[tid]  = w2[o * 60 + i] * inv2;
    sW3h2[tid] = w3[o * 72 + i];
    sW3h1[tid] = w3[o * 72 + 12 + i];
  }
  __syncthreads();
  int k = tid & 15, pl = tid >> 4;
  int p = blockIdx.x * 16 + pl;
  int b = p >> 11, n = p & (NPTS - 1);
  int nb = knn[(size_t)p * KNB + k];
  const float4* u4 = (const float4*)(aux + (size_t)p * 72);
  const float4* a4 = (const float4*)(aux + ((size_t)(b << 11) + nb) * 72 + 36);
  float uc[36], av[36];
#pragma unroll
  for (int i = 0; i < 9; ++i) {
    float4 t = u4[i];
    uc[4*i] = t.x; uc[4*i+1] = t.y; uc[4*i+2] = t.z; uc[4*i+3] = t.w;
    float4 t2 = a4[i];
    av[4*i] = t2.x; av[4*i+1] = t2.y; av[4*i+2] = t2.z; av[4*i+3] = t2.w;
  }
  float h1[12], h2[12], h3[12];
#pragma unroll
  for (int o = 0; o < 12; ++o) h1[o] = fmaxf(uc[o] + av[o], 0.f);
#pragma unroll
  for (int o = 0; o < 12; ++o) {
    float a = uc[12 + o] + av[12 + o];
#pragma unroll
    for (int i = 0; i < 12; ++i) a = fmaf(sW2h[o * 12 + i], h1[i], a);
    h2[o] = fmaxf(a, 0.f);
  }
#pragma unroll
  for (int o = 0; o < 12; ++o) {
    float a = uc[24 + o] + av[24 + o];
#pragma unroll
    for (int i = 0; i < 12; ++i) a = fmaf(sW3h2[o * 12 + i], h2[i], a);
#pragma unroll
    for (int i = 0; i < 12; ++i) a = fmaf(sW3h1[o * 12 + i], h1[i], a);
    h3[o] = a;
  }
  float nbf[24];
  const float4* pn4 = (const float4*)(pre + ((size_t)(b << 11) + nb) * 24);
#pragma unroll
  for (int i = 0; i < 6; ++i) {
    float4 t = pn4[i];
    nbf[4*i] = t.x; nbf[4*i+1] = t.y; nbf[4*i+2] = t.z; nbf[4*i+3] = t.w;
  }
#pragma unroll
  for (int m = 1; m < 16; m <<= 1) {
#pragma unroll
    for (int o = 0; o < 12; ++o) {
      h1[o] = fmaxf(h1[o], __shfl_xor(h1[o], m, 16));
      h2[o] = fmaxf(h2[o], __shfl_xor(h2[o], m, 16));
      h3[o] = fmaxf(h3[o], __shfl_xor(h3[o], m, 16));
    }
#pragma unroll
    for (int i = 0; i < 24; ++i)
      nbf[i] = fmaxf(nbf[i], __shfl_xor(nbf[i], m, 16));
  }
  if (k == 0) {
    const float4* c4 = (const float4*)(pre + (size_t)p * 24);
#pragma unroll
    for (int o = 0; o < 12; ++o) {
      sout[(0  + o) * 16 + pl] = h3[o];
      sout[(12 + o) * 16 + pl] = h2[o];
      sout[(24 + o) * 16 + pl] = h1[o];
    }
#pragma unroll
    for (int i = 0; i < 6; ++i) {
      float4 t = c4[i];
      sout[(36 + 4*i    ) * 16 + pl] = t.x;
      sout[(36 + 4*i + 1) * 16 + pl] = t.y;
      sout[(36 + 4*i + 2) * 16 + pl] = t.z;
      sout[(36 + 4*i + 3) * 16 + pl] = t.w;
    }
#pragma unroll
    for (int i = 0; i < 24; ++i) sout[(60 + i) * 16 + pl] = nbf[i];
    const float* xb = x + (size_t)b * 3 * NPTS + n;
    sout[84 * 16 + pl] = xb[0];
    sout[85 * 16 + pl] = xb[NPTS];
    sout[86 * 16 + pl] = xb[2 * NPTS];
  }
  __syncthreads();
  int n0 = (blockIdx.x * 16) & (NPTS - 1);
  float* ob = out + (size_t)b * 87 * NPTS;
  for (int j2 = tid; j2 < 87 * 16; j2 += 256) {
    int c = j2 >> 4, i = j2 & 15;
    ob[(size_t)c * NPTS + n0 + i] = sout[j2];
  }
}

extern "C" void kernel_launch(void* const* d_in, const int* in_sizes, int n_in,
                              void* d_out, int out_size, void* d_ws, size_t ws_size,
                              hipStream_t stream) {
  (void)in_sizes; (void)n_in; (void)out_size; (void)ws_size;
  const float* x     = (const float*)d_in[0];
  const float* w_pre = (const float*)d_in[1];
  const float* b_pre = (const float*)d_in[2];
  const float* g_pre = (const float*)d_in[3];
  const float* be_pre= (const float*)d_in[4];
  const float* m_pre = (const float*)d_in[5];
  const float* v_pre = (const float*)d_in[6];
  const float* w1    = (const float*)d_in[7];
  const float* g1    = (const float*)d_in[8];
  const float* be1   = (const float*)d_in[9];
  const float* m1    = (const float*)d_in[10];
  const float* v1    = (const float*)d_in[11];
  const float* w2    = (const float*)d_in[12];
  const float* g2    = (const float*)d_in[13];
  const float* be2   = (const float*)d_in[14];
  const float* m2    = (const float*)d_in[15];
  const float* v2    = (const float*)d_in[16];
  const float* w3    = (const float*)d_in[17];
  float* ws  = (float*)d_ws;
  float* pre = ws + WS_PRE;
  float* aux = ws + WS_AUX;
  int*   knn = (int*)(ws + WS_IDX);
  float* out = (float*)d_out;

  knnpre_kernel<<<NBATCH * 64, 512, 0, stream>>>(
      x, w_pre, b_pre, g_pre, be_pre, m_pre, v_pre,
      w1, g1, be1, m1, v1, w2, g2, be2, m2, v2, w3,
      pre, aux, knn);
  mlp_kernel<<<NBATCH * NPTS / 16, 256, 0, stream>>>(pre, aux, knn, x,
                                                     w2, g2, v2, w3, out);
}